// Round 4
// baseline (131.730 us; speedup 1.0000x reference)
//
#include <hip/hip_runtime.h>

// 4-level db4 wavedec (symmetric mode) + 6 stats per band.
// One block of 512 threads per signal. Levels: 16384 -> 8195 -> 4101 -> 2054 -> 1030.
//
// V5 = V3 skeleton (ping-pong LDS, 4 barriers, quad-per-thread @90us) with ONE
// change: packed-FP32 dot products. gfx950 (CDNA4) has v_pk_fma_f32; pairing
// (a_i, d_i) in one v2f accumulator shares the window element v[j] across both
// halves (splat -> op_sel-foldable) and the (FLO[m],FHI[m]) constant pair sits
// in SGPR pairs. 72 scalar FMA/quad -> 40 pk_fma/quad; accumulation order (m
// ascending per output) identical to V3 -> bitwise-same results.
// V4's in-place single-buffer experiment REGRESSED (103us): 5 extra full-block
// barrier drains with pending writes held across them beat the occupancy gain.
// Ping-pong + 1 barrier/level is load-bearing; do not re-break it.
// Band order: [cA4, cD4, cD3, cD2, cD1] x [mean_abs, std, rms, max, energy, zc].

#define T0 16384
#define BLK 512
#define NW (BLK / 64)

typedef float v2f __attribute__((ext_vector_type(2)));

// Reversed db4 decomposition filters (lax correlation == pywt convolution).
constexpr float FLO[8] = {
     0.23037781330885523f,  0.7148465705525415f,   0.6308807679295904f,
    -0.02798376941698385f, -0.18703481171888114f,  0.030841381835986965f,
     0.032883011666982945f, -0.010597401784997278f };
constexpr float FHI[8] = {
    -0.010597401784997278f, -0.032883011666982945f, 0.030841381835986965f,
     0.18703481171888114f,  -0.02798376941698385f,  -0.6308807679295904f,
     0.7148465705525415f,   -0.23037781330885523f };

// symmetric extension fold: ext index t -> valid index (single fold suffices;
// our windows stay within [-6, L+10]).
__device__ __forceinline__ float getsym(const float* __restrict__ s, int t, int L) {
    if (t < 0) t = -1 - t;
    else if (t >= L) t = 2 * L - 1 - t;
    return s[t];
}

// 1 if sign bits differ (zero-crossing). Matches sign()-diff for nonzero data.
__device__ __forceinline__ float zcstep(float p, float q) {
    return ((__float_as_int(p) ^ __float_as_int(q)) < 0) ? 1.f : 0.f;
}

// Wave-level butterfly reduce of the 5 partials; lane0 of each wave writes
// its slot in red[band][wave][5]. NO barrier here (deferred to finalize).
__device__ __forceinline__ void band_reduce(float sabs, float ssum, float ssq,
                                            float smax, float zc,
                                            int band, float* __restrict__ red) {
    #pragma unroll
    for (int off = 32; off > 0; off >>= 1) {
        sabs += __shfl_xor(sabs, off, 64);
        ssum += __shfl_xor(ssum, off, 64);
        ssq  += __shfl_xor(ssq,  off, 64);
        smax  = fmaxf(smax, __shfl_xor(smax, off, 64));
        zc   += __shfl_xor(zc,   off, 64);
    }
    const int lane = threadIdx.x & 63;
    const int wave = threadIdx.x >> 6;
    if (lane == 0) {
        float* r = red + (band * NW + wave) * 5;
        r[0] = sabs; r[1] = ssum; r[2] = ssq; r[3] = smax; r[4] = zc;
    }
}

// Load the 20-float window for quad k: v[j] = src_ext[8k-8+j]. Fast path is
// 5x float4 (16B aligned, 32B lane stride -> conflict-free b128 in LDS);
// boundary threads take the folded scalar path (only v[2..17] are consumed).
__device__ __forceinline__ void load_win(const float* __restrict__ src, int L, int k,
                                         float* __restrict__ v) {
    const int w = 8 * k - 8;
    if (w >= 0 && w + 20 <= L) {
        #pragma unroll
        for (int q = 0; q < 5; ++q) {
            const float4 t = *reinterpret_cast<const float4*>(src + w + 4 * q);
            v[4*q+0] = t.x; v[4*q+1] = t.y; v[4*q+2] = t.z; v[4*q+3] = t.w;
        }
    } else {
        #pragma unroll
        for (int j = 2; j < 18; ++j) v[j] = getsym(src, w + j, L);
    }
}

// Packed dots for one quad: acc[i] = (a_i, d_i), i=0..4 (i=4 is the zc/LAST
// extra). Each pk_fma does the lo- and hi-filter MAC for one output position;
// the splat vv[j] is shared across all accumulators that use v[j+2], and the
// (FLO,FHI) pair is a hoisted SGPR-pair constant. m ascending == V3 order.
__device__ __forceinline__ void quad_dots_pk(const float* __restrict__ v,
                                             v2f* __restrict__ acc) {
    v2f vv[16];
    #pragma unroll
    for (int j = 0; j < 16; ++j) vv[j] = (v2f){v[j + 2], v[j + 2]};
    #pragma unroll
    for (int i = 0; i < 5; ++i) acc[i] = (v2f){0.f, 0.f};
    #pragma unroll
    for (int i = 0; i < 5; ++i) {
        #pragma unroll
        for (int m = 0; m < 8; ++m) {
            const v2f C = {FLO[m], FHI[m]};
            acc[i] = __builtin_elementwise_fma(vv[2 * i + m], C, acc[i]);
        }
    }
}

// Scalar dots (cold tail path only).
__device__ __forceinline__ void quad_dots_tail(const float* __restrict__ v,
                                               float* __restrict__ a, float* __restrict__ d) {
    #pragma unroll
    for (int i = 0; i < 5; ++i) { a[i] = 0.f; d[i] = 0.f; }
    #pragma unroll
    for (int i = 0; i < 5; ++i) {
        #pragma unroll
        for (int m = 0; m < 8; ++m) {
            a[i] = fmaf(v[2*i+2+m], FLO[m], a[i]);
            d[i] = fmaf(v[2*i+2+m], FHI[m], d[i]);
        }
    }
}

// One DWT level, quad-per-thread, packed dots.
// LAST: also accumulate cA stats into band 0 and skip the dst write.
template<bool LAST>
__device__ __forceinline__ void dwt_quad_level(const float* __restrict__ src, int L,
                                               float* __restrict__ dst, int o,
                                               int dband, float* __restrict__ red) {
    float sabs = 0.f, ssum = 0.f, ssq = 0.f, smax = 0.f, zc = 0.f;       // cD stats
    float sabsA = 0.f, ssumA = 0.f, ssqA = 0.f, smaxA = 0.f, zcA = 0.f;  // cA stats (LAST)
    const int nq_main = (o - 1) >> 2;   // quads with 4 valid outputs AND valid extra

    for (int k = threadIdx.x; k < nq_main; k += BLK) {
        float v[20];
        v2f acc[5];
        load_win(src, L, k, v);
        quad_dots_pk(v, acc);
        if constexpr (!LAST) {
            *reinterpret_cast<float4*>(dst + 4 * k) =
                make_float4(acc[0][0], acc[1][0], acc[2][0], acc[3][0]);
        }
        #pragma unroll
        for (int i = 0; i < 4; ++i) {
            const float di = acc[i][1];
            const float ad = fabsf(di);
            sabs += ad; ssum += di; ssq = fmaf(di, di, ssq);
            smax = fmaxf(smax, ad);
            zc += zcstep(di, acc[i + 1][1]);
            if constexpr (LAST) {
                const float ai = acc[i][0];
                const float aa = fabsf(ai);
                sabsA += aa; ssumA += ai; ssqA = fmaf(ai, ai, ssqA);
                smaxA = fmaxf(smaxA, aa);
                zcA += zcstep(ai, acc[i + 1][0]);
            }
        }
    }

    // Exactly ONE leftover quad per level for our sizes: nq-nq_main == 1.
    // Run it guarded on thread BLK-1 (low threads absorb main-loop remainders).
    if (threadIdx.x == BLK - 1) {
        const int k = nq_main;
        const int w = 8 * k - 8;
        float v[20], a[5], d[5];
        #pragma unroll
        for (int j = 2; j < 18; ++j) v[j] = getsym(src, w + j, L);
        quad_dots_tail(v, a, d);
        #pragma unroll
        for (int i = 0; i < 4; ++i) {
            const int p = 4 * k + i;
            if (p < o) {
                const float ad = fabsf(d[i]);
                sabs += ad; ssum += d[i]; ssq = fmaf(d[i], d[i], ssq);
                smax = fmaxf(smax, ad);
                if (p + 1 < o) zc += zcstep(d[i], d[i+1]);
                if constexpr (LAST) {
                    const float aa = fabsf(a[i]);
                    sabsA += aa; ssumA += a[i]; ssqA = fmaf(a[i], a[i], ssqA);
                    smaxA = fmaxf(smaxA, aa);
                    if (p + 1 < o) zcA += zcstep(a[i], a[i+1]);
                } else {
                    dst[p] = a[i];
                }
            }
        }
    }

    band_reduce(sabs, ssum, ssq, smax, zc, dband, red);
    if constexpr (LAST) band_reduce(sabsA, ssumA, ssqA, smaxA, zcA, 0, red);
}

__global__ void __launch_bounds__(BLK, 6)
wavelet_feat_kernel(const float* __restrict__ x, float* __restrict__ out) {
    __shared__ __align__(16) float A[8196];     // cA1, later cA3
    __shared__ __align__(16) float B[4104];     // cA2
    __shared__ float red[5 * NW * 5];           // [band][wave][stat]

    const int sig = blockIdx.x;
    const float* src0 = x + (size_t)sig * T0;
    float* outp = out + (size_t)sig * 30;

    // band index: 0=cA4 1=cD4 2=cD3 3=cD2 4=cD1
    dwt_quad_level<false>(src0, T0,   A, 8195, 4, red);   // L1: x -> A,  cD1
    __syncthreads();
    dwt_quad_level<false>(A,    8195, B, 4101, 3, red);   // L2: A -> B,  cD2
    __syncthreads();
    dwt_quad_level<false>(B,    4101, A, 2054, 2, red);   // L3: B -> A,  cD3
    __syncthreads();
    dwt_quad_level<true >(A,    2054, nullptr, 1030, 1, red); // L4: cD4 + cA4 stats
    __syncthreads();                                      // red[] complete

    if (threadIdx.x < 5) {
        const int band = threadIdx.x;
        float a = 0.f, s = 0.f, q = 0.f, m = 0.f, z = 0.f;
        #pragma unroll
        for (int w = 0; w < NW; ++w) {
            const float* r = red + (band * NW + w) * 5;
            a += r[0]; s += r[1]; q += r[2]; m = fmaxf(m, r[3]); z += r[4];
        }
        const int o = (band <= 1) ? 1030 : (band == 2 ? 2054 : (band == 3 ? 4101 : 8195));
        const float inv  = 1.0f / (float)o;
        const float mean = s * inv;
        const float var  = q * inv - mean * mean;
        float* op = outp + band * 6;
        op[0] = a * inv;                  // mean_abs
        op[1] = sqrtf(fmaxf(var, 0.f));   // std (population)
        op[2] = sqrtf(q * inv);           // rms
        op[3] = m;                        // max_abs
        op[4] = q;                        // energy
        op[5] = z * inv;                  // zero-crossing rate
    }
}

extern "C" void kernel_launch(void* const* d_in, const int* in_sizes, int n_in,
                              void* d_out, int out_size, void* d_ws, size_t ws_size,
                              hipStream_t stream) {
    const float* x = (const float*)d_in[0];
    float* out = (float*)d_out;
    const int nsig = in_sizes[0] / T0;   // 64*64 = 4096
    hipLaunchKernelGGL(wavelet_feat_kernel, dim3(nsig), dim3(BLK), 0, stream, x, out);
}

// Round 5
// 131.293 us; speedup vs baseline: 1.0033x; 1.0033x over previous
//
#include <hip/hip_runtime.h>

// 4-level db4 wavedec (symmetric mode) + 6 stats per band.
// One block of 512 threads per signal. Levels: 16384 -> 8195 -> 4101 -> 2054 -> 1030.
//
// V6 = V3's proven skeleton (scalar-FMA quad-per-thread dots, shfl_xor reduce,
// @90us) with ONE structural change: single LDS buffer A[8196] using
// LEVEL-granularity hold-in-registers in-place updates:
//   compute ALL quads of the level (reads at full memory-level parallelism,
//   outputs held in regs) -> barrier -> batch-write cA -> barrier.
// Race-free by construction (every read of the level precedes every write).
// LDS 50.2KB -> 33.6KB => 4 blocks/CU = 32 waves/CU (8/SIMD, +33% vs V3's 6)
// at the cost of exactly +1 barrier (6 vs 5 total).
// History: V4 (per-CHUNK read/bar/write phases, +5 barriers) regressed to
// 103us -- chunk-serialized MLP. V5 (packed v2f dots) regressed to 131us --
// scratch spill (WRITE_SIZE 22.9MB) + LDS conflicts 2.7e7. Both reverted.
// Band order: [cA4, cD4, cD3, cD2, cD1] x [mean_abs, std, rms, max, energy, zc].

#define T0 16384
#define BLK 512
#define NW (BLK / 64)

// Reversed db4 decomposition filters (lax correlation == pywt convolution).
constexpr float FLO[8] = {
     0.23037781330885523f,  0.7148465705525415f,   0.6308807679295904f,
    -0.02798376941698385f, -0.18703481171888114f,  0.030841381835986965f,
     0.032883011666982945f, -0.010597401784997278f };
constexpr float FHI[8] = {
    -0.010597401784997278f, -0.032883011666982945f, 0.030841381835986965f,
     0.18703481171888114f,  -0.02798376941698385f,  -0.6308807679295904f,
     0.7148465705525415f,   -0.23037781330885523f };

// symmetric extension fold: ext index t -> valid index (single fold suffices;
// our windows stay within [-6, L+10]).
__device__ __forceinline__ float getsym(const float* __restrict__ s, int t, int L) {
    if (t < 0) t = -1 - t;
    else if (t >= L) t = 2 * L - 1 - t;
    return s[t];
}

// 1 if sign bits differ (zero-crossing). Matches sign()-diff for nonzero data.
__device__ __forceinline__ float zcstep(float p, float q) {
    return ((__float_as_int(p) ^ __float_as_int(q)) < 0) ? 1.f : 0.f;
}

// Wave-level butterfly reduce of the 5 partials; lane0 of each wave writes
// its slot in red[band][wave][5]. NO barrier here (deferred to finalize).
__device__ __forceinline__ void band_reduce(float sabs, float ssum, float ssq,
                                            float smax, float zc,
                                            int band, float* __restrict__ red) {
    #pragma unroll
    for (int off = 32; off > 0; off >>= 1) {
        sabs += __shfl_xor(sabs, off, 64);
        ssum += __shfl_xor(ssum, off, 64);
        ssq  += __shfl_xor(ssq,  off, 64);
        smax  = fmaxf(smax, __shfl_xor(smax, off, 64));
        zc   += __shfl_xor(zc,   off, 64);
    }
    const int lane = threadIdx.x & 63;
    const int wave = threadIdx.x >> 6;
    if (lane == 0) {
        float* r = red + (band * NW + wave) * 5;
        r[0] = sabs; r[1] = ssum; r[2] = ssq; r[3] = smax; r[4] = zc;
    }
}

// Load the 20-float window for quad k: v[j] = src_ext[8k-8+j]. Fast path is
// 5x float4 (16B aligned, 32B lane stride -> conflict-free b128 in LDS);
// boundary threads take the folded scalar path (only v[2..17] are consumed).
__device__ __forceinline__ void load_win(const float* __restrict__ src, int L, int k,
                                         float* __restrict__ v) {
    const int w = 8 * k - 8;
    if (w >= 0 && w + 20 <= L) {
        #pragma unroll
        for (int q = 0; q < 5; ++q) {
            const float4 t = *reinterpret_cast<const float4*>(src + w + 4 * q);
            v[4*q+0] = t.x; v[4*q+1] = t.y; v[4*q+2] = t.z; v[4*q+3] = t.w;
        }
    } else {
        #pragma unroll
        for (int j = 2; j < 18; ++j) v[j] = getsym(src, w + j, L);
    }
}

// a[0..3], d[0..4] (+a[4] if LAST) for one quad from window v[2..17].
// Scalar FMAs, m ascending -- proven codegen (V3).
template<bool LAST>
__device__ __forceinline__ void quad_dots(const float* __restrict__ v,
                                          float* __restrict__ a, float* __restrict__ d) {
    #pragma unroll
    for (int i = 0; i < 5; ++i) { a[i] = 0.f; d[i] = 0.f; }
    #pragma unroll
    for (int i = 0; i < 4; ++i) {
        #pragma unroll
        for (int m = 0; m < 8; ++m) {
            a[i] = fmaf(v[2*i+2+m], FLO[m], a[i]);
            d[i] = fmaf(v[2*i+2+m], FHI[m], d[i]);
        }
    }
    #pragma unroll
    for (int m = 0; m < 8; ++m) {
        d[4] = fmaf(v[10+m], FHI[m], d[4]);
        if constexpr (LAST) a[4] = fmaf(v[10+m], FLO[m], a[4]);
    }
}

// Full 5-dot version for cold tail paths.
__device__ __forceinline__ void quad_dots_tail(const float* __restrict__ v,
                                               float* __restrict__ a, float* __restrict__ d) {
    #pragma unroll
    for (int i = 0; i < 5; ++i) { a[i] = 0.f; d[i] = 0.f; }
    #pragma unroll
    for (int i = 0; i < 5; ++i) {
        #pragma unroll
        for (int m = 0; m < 8; ++m) {
            a[i] = fmaf(v[2*i+2+m], FLO[m], a[i]);
            d[i] = fmaf(v[2*i+2+m], FHI[m], d[i]);
        }
    }
}

// Level 1 (and stats-only L4): V3's dwt_quad_level, verbatim behavior.
// L1: src=global x, dst=LDS A -> immediate writes, no hazard, no barriers.
// LAST: stats only (cD into dband, cA into band 0), dst unused.
template<bool LAST>
__device__ __forceinline__ void dwt_quad_level(const float* __restrict__ src, int L,
                                               float* __restrict__ dst, int o,
                                               int dband, float* __restrict__ red) {
    float sabs = 0.f, ssum = 0.f, ssq = 0.f, smax = 0.f, zc = 0.f;       // cD stats
    float sabsA = 0.f, ssumA = 0.f, ssqA = 0.f, smaxA = 0.f, zcA = 0.f;  // cA stats (LAST)
    const int nq_main = (o - 1) >> 2;

    for (int k = threadIdx.x; k < nq_main; k += BLK) {
        float v[20], a[5], d[5];
        load_win(src, L, k, v);
        quad_dots<LAST>(v, a, d);
        if constexpr (!LAST) {
            *reinterpret_cast<float4*>(dst + 4 * k) = make_float4(a[0], a[1], a[2], a[3]);
        }
        #pragma unroll
        for (int i = 0; i < 4; ++i) {
            const float ad = fabsf(d[i]);
            sabs += ad; ssum += d[i]; ssq = fmaf(d[i], d[i], ssq);
            smax = fmaxf(smax, ad);
            zc += zcstep(d[i], d[i + 1]);
            if constexpr (LAST) {
                const float aa = fabsf(a[i]);
                sabsA += aa; ssumA += a[i]; ssqA = fmaf(a[i], a[i], ssqA);
                smaxA = fmaxf(smaxA, aa);
                zcA += zcstep(a[i], a[i + 1]);
            }
        }
    }

    if (threadIdx.x == BLK - 1) {       // exactly one leftover quad per level
        const int k = nq_main;
        float v[20], a[5], d[5];
        #pragma unroll
        for (int j = 2; j < 18; ++j) v[j] = getsym(src, 8 * k - 8 + j, L);
        quad_dots_tail(v, a, d);
        #pragma unroll
        for (int i = 0; i < 4; ++i) {
            const int p = 4 * k + i;
            if (p < o) {
                const float ad = fabsf(d[i]);
                sabs += ad; ssum += d[i]; ssq = fmaf(d[i], d[i], ssq);
                smax = fmaxf(smax, ad);
                if (p + 1 < o) zc += zcstep(d[i], d[i+1]);
                if constexpr (LAST) {
                    const float aa = fabsf(a[i]);
                    sabsA += aa; ssumA += a[i]; ssqA = fmaf(a[i], a[i], ssqA);
                    smaxA = fmaxf(smaxA, aa);
                    if (p + 1 < o) zcA += zcstep(a[i], a[i+1]);
                } else {
                    dst[p] = a[i];
                }
            }
        }
    }

    band_reduce(sabs, ssum, ssq, smax, zc, dband, red);
    if constexpr (LAST) band_reduce(sabsA, ssumA, ssqA, smaxA, zcA, 0, red);
}

// In-place level in A with LEVEL-granularity hold-write:
//   compute all quads (outputs held in regs, reads fully parallel)
//   -> barrier -> batch write A[0..o) -> barrier.
// Ends with the writes visible: next level may read A immediately.
template<int L, int o, int DBAND>
__device__ __forceinline__ void dwt_hold_level(float* __restrict__ A,
                                               float* __restrict__ red) {
    float sabs = 0.f, ssum = 0.f, ssq = 0.f, smax = 0.f, zc = 0.f;
    constexpr int NQ = (o - 1) >> 2;               // 1025 (L2) / 513 (L3)
    constexpr int NI = (NQ + BLK - 1) / BLK;       // 3 / 2
    const int tid = (int)threadIdx.x;

    float hq[NI][4];                               // held cA quads (static idx)
    float tq[4];                                   // held tail (thread 511)

    // ---- compute phase: NO barriers, NO writes ----
    #pragma unroll
    for (int c = 0; c < NI; ++c) {
        const int k = c * BLK + tid;
        if (k < NQ) {
            float v[20], a[5], d[5];
            load_win(A, L, k, v);
            quad_dots<false>(v, a, d);
            #pragma unroll
            for (int i = 0; i < 4; ++i) {
                const float ad = fabsf(d[i]);
                sabs += ad; ssum += d[i]; ssq = fmaf(d[i], d[i], ssq);
                smax = fmaxf(smax, ad);
                zc += zcstep(d[i], d[i + 1]);
                hq[c][i] = a[i];
            }
        }
    }
    if (tid == BLK - 1) {                          // tail quad k=NQ, guarded
        float v[20], a[5], d[5];
        #pragma unroll
        for (int j = 2; j < 18; ++j) v[j] = getsym(A, 8 * NQ - 8 + j, L);
        quad_dots_tail(v, a, d);
        #pragma unroll
        for (int i = 0; i < 4; ++i) {
            const int p = 4 * NQ + i;
            if (p < o) {
                const float ad = fabsf(d[i]);
                sabs += ad; ssum += d[i]; ssq = fmaf(d[i], d[i], ssq);
                smax = fmaxf(smax, ad);
                if (p + 1 < o) zc += zcstep(d[i], d[i + 1]);
            }
            tq[i] = a[i];
        }
    }

    // ---- write phase ----
    __syncthreads();                               // all level reads complete
    #pragma unroll
    for (int c = 0; c < NI; ++c) {
        const int k = c * BLK + tid;
        if (k < NQ)
            *reinterpret_cast<float4*>(A + 4 * k) =
                make_float4(hq[c][0], hq[c][1], hq[c][2], hq[c][3]);
    }
    if (tid == BLK - 1) {
        #pragma unroll
        for (int i = 0; i < 4; ++i)
            if (4 * NQ + i < o) A[4 * NQ + i] = tq[i];
    }
    __syncthreads();                               // writes visible downstream

    band_reduce(sabs, ssum, ssq, smax, zc, DBAND, red);
}

__global__ void __launch_bounds__(BLK, 8)
wavelet_feat_kernel(const float* __restrict__ x, float* __restrict__ out) {
    __shared__ __align__(16) float A[8196];        // all cascade levels, in place
    __shared__ float red[5 * NW * 5];              // [band][wave][stat]

    const int sig = blockIdx.x;
    const float* src0 = x + (size_t)sig * T0;
    float* outp = out + (size_t)sig * 30;

    // band index: 0=cA4 1=cD4 2=cD3 3=cD2 4=cD1
    dwt_quad_level<false>(src0, T0, A, 8195, 4, red);   // L1: x -> A, cD1
    __syncthreads();
    dwt_hold_level<8195, 4101, 3>(A, red);              // L2 in place, cD2
    dwt_hold_level<4101, 2054, 2>(A, red);              // L3 in place, cD3
    dwt_quad_level<true>(A, 2054, nullptr, 1030, 1, red); // L4: cD4 + cA4 stats
    __syncthreads();                                    // red[] complete

    if (threadIdx.x < 5) {
        const int band = (int)threadIdx.x;
        float a = 0.f, s = 0.f, q = 0.f, m = 0.f, z = 0.f;
        #pragma unroll
        for (int w = 0; w < NW; ++w) {
            const float* r = red + (band * NW + w) * 5;
            a += r[0]; s += r[1]; q += r[2]; m = fmaxf(m, r[3]); z += r[4];
        }
        const int o = (band <= 1) ? 1030 : (band == 2 ? 2054 : (band == 3 ? 4101 : 8195));
        const float inv  = 1.0f / (float)o;
        const float mean = s * inv;
        const float var  = q * inv - mean * mean;
        float* op = outp + band * 6;
        op[0] = a * inv;                  // mean_abs
        op[1] = sqrtf(fmaxf(var, 0.f));   // std (population)
        op[2] = sqrtf(q * inv);           // rms
        op[3] = m;                        // max_abs
        op[4] = q;                        // energy
        op[5] = z * inv;                  // zero-crossing rate
    }
}

extern "C" void kernel_launch(void* const* d_in, const int* in_sizes, int n_in,
                              void* d_out, int out_size, void* d_ws, size_t ws_size,
                              hipStream_t stream) {
    const float* x = (const float*)d_in[0];
    float* out = (float*)d_out;
    const int nsig = in_sizes[0] / T0;   // 64*64 = 4096
    hipLaunchKernelGGL(wavelet_feat_kernel, dim3(nsig), dim3(BLK), 0, stream, x, out);
}

// Round 6
// 91.809 us; speedup vs baseline: 1.4348x; 1.4301x over previous
//
#include <hip/hip_runtime.h>

// 4-level db4 wavedec (symmetric mode) + 6 stats per band.
// One block of 512 threads per signal. Levels: 16384 -> 8195 -> 4101 -> 2054 -> 1030.
//
// V7 = V3's proven shell (ping-pong LDS A/B, 1 barrier/level, shfl_xor reduce,
// launch_bounds(512,6)) with the work decomposition rebuilt around CONTIGUOUS
// SPANS + XOR-swizzled LDS:
//  - thread t owns outputs [S*t, S*t+S), S = 16/8/4/4 per level. Adjacent
//    output windows overlap 6 floats each -> span of S outputs needs only
//    2S+12 input floats (vs 5 per output strided): loads/output 5 -> 2.9,
//    d-dots S+1 per span (zc extra amortized over the span, not per quad),
//    no inner loop (one straight-line region per thread).
//  - contiguous spans => 128B LDS lane stride = 32-way bank conflict, so ALL
//    LDS cA storage goes through a float4-granule XOR swizzle
//    (i4 ^ (i4>>3)&7), same function on write and read -> verified 8 lanes
//    per 4-bank group for every level's read AND write pattern.
//  - boundaries: t==0 loads shifted f4s and mirrors v[0..7] in registers;
//    the tail thread loads clamped f4s and mirrors the right fold. No
//    per-element getsym path anywhere.
//  - zc: per-span sign-bit mask + popc(mask ^ (mask>>1)).
// History: V4 (in-place per-chunk barriers) 103us; V5 (packed v2f) 131us,
// scratch spill; V6 (hold-in-regs + launch_bounds(512,8)) 131us, spill
// (WRITE_SIZE 182MB). Occupancy>3blk/CU is unreachable; this attacks issue count.
// Band order: [cA4, cD4, cD3, cD2, cD1] x [mean_abs, std, rms, max, energy, zc].

#define T0 16384
#define BLK 512
#define NW (BLK / 64)

// Reversed db4 decomposition filters (lax correlation == pywt convolution).
constexpr float FLO[8] = {
     0.23037781330885523f,  0.7148465705525415f,   0.6308807679295904f,
    -0.02798376941698385f, -0.18703481171888114f,  0.030841381835986965f,
     0.032883011666982945f, -0.010597401784997278f };
constexpr float FHI[8] = {
    -0.010597401784997278f, -0.032883011666982945f, 0.030841381835986965f,
     0.18703481171888114f,  -0.02798376941698385f,  -0.6308807679295904f,
     0.7148465705525415f,   -0.23037781330885523f };

// float4-granule XOR swizzle: spreads 128B-strided lanes across bank groups.
#define SWZ(i4) ((i4) ^ (((i4) >> 3) & 7))

__device__ __forceinline__ float4 lds_read4(const float* __restrict__ A, int i4) {
    return reinterpret_cast<const float4*>(A)[SWZ(i4)];
}
__device__ __forceinline__ void lds_write4(float* __restrict__ A, int i4, float4 t) {
    reinterpret_cast<float4*>(A)[SWZ(i4)] = t;
}
__device__ __forceinline__ void lds_write1(float* __restrict__ A, int f, float t) {
    A[4 * SWZ(f >> 2) + (f & 3)] = t;
}

struct Acc { float sabs, ssum, ssq, smax, zc; };

// Wave-level butterfly reduce; lane0 of each wave writes red[band][wave][5].
// NO barrier here (deferred to finalize).
__device__ __forceinline__ void band_reduce(Acc a, int band, float* __restrict__ red) {
    #pragma unroll
    for (int off = 32; off > 0; off >>= 1) {
        a.sabs += __shfl_xor(a.sabs, off, 64);
        a.ssum += __shfl_xor(a.ssum, off, 64);
        a.ssq  += __shfl_xor(a.ssq,  off, 64);
        a.smax  = fmaxf(a.smax, __shfl_xor(a.smax, off, 64));
        a.zc   += __shfl_xor(a.zc,   off, 64);
    }
    const int lane = threadIdx.x & 63;
    const int wave = threadIdx.x >> 6;
    if (lane == 0) {
        float* r = red + (band * NW + wave) * 5;
        r[0] = a.sabs; r[1] = a.ssum; r[2] = a.ssq; r[3] = a.smax; r[4] = a.zc;
    }
}

// Core: NOUT outputs from window v[], v[j] = src_ext[2*p0 - 8 + j].
// Output p0+i uses v[2i+2 .. 2i+9]. EXTRA: one more d (and a if LAST) dot at
// p0+NOUT for the span-boundary zc pair. Stats on d (and a if LAST); cA
// written f4-swizzled (VECW, p0 % 4 == 0) or scalar-swizzled (tail).
template<int NOUT, bool EXTRA, bool LAST, bool VECW>
__device__ __forceinline__ void span_core(const float* __restrict__ v,
                                          float* __restrict__ dst, int p0,
                                          Acc& aD, Acc& aA) {
    unsigned dm = 0, am = 0;
    float aq[4];
    #pragma unroll
    for (int i = 0; i < NOUT; ++i) {
        float a = 0.f, d = 0.f;
        #pragma unroll
        for (int m = 0; m < 8; ++m) {
            a = fmaf(v[2*i+2+m], FLO[m], a);
            d = fmaf(v[2*i+2+m], FHI[m], d);
        }
        dm = (dm << 1) | (__float_as_uint(d) >> 31);
        aD.sabs += fabsf(d); aD.ssum += d; aD.ssq = fmaf(d, d, aD.ssq);
        aD.smax = fmaxf(aD.smax, fabsf(d));
        if constexpr (LAST) {
            am = (am << 1) | (__float_as_uint(a) >> 31);
            aA.sabs += fabsf(a); aA.ssum += a; aA.ssq = fmaf(a, a, aA.ssq);
            aA.smax = fmaxf(aA.smax, fabsf(a));
        } else if constexpr (VECW) {
            aq[i & 3] = a;
            if ((i & 3) == 3)
                lds_write4(dst, (p0 >> 2) + (i >> 2),
                           make_float4(aq[0], aq[1], aq[2], aq[3]));
        } else {
            lds_write1(dst, p0 + i, a);
        }
    }
    if constexpr (EXTRA) {
        float d = 0.f;
        #pragma unroll
        for (int m = 0; m < 8; ++m) d = fmaf(v[2*NOUT+2+m], FHI[m], d);
        dm = (dm << 1) | (__float_as_uint(d) >> 31);
        if constexpr (LAST) {
            float a = 0.f;
            #pragma unroll
            for (int m = 0; m < 8; ++m) a = fmaf(v[2*NOUT+2+m], FLO[m], a);
            am = (am << 1) | (__float_as_uint(a) >> 31);
        }
    }
    constexpr int NP = EXTRA ? NOUT : NOUT - 1;   // owned zc pairs
    if constexpr (NP > 0) {
        aD.zc += (float)__popc((dm ^ (dm >> 1)) & ((1u << NP) - 1u));
        if constexpr (LAST)
            aA.zc += (float)__popc((am ^ (am >> 1)) & ((1u << NP) - 1u));
    }
}

// One DWT level. Threads 0..NT-2: span S (t==0 left-mirrors in registers).
// Thread NT-1: tail span SN = o - S*(NT-1) with right fold mirrored in
// registers (LDS over-reads land in the padded region; global loads are
// clamped). Threads >= NT idle (contribute zeros to the reduce).
template<int S, int NT, int L, int o, bool LAST, bool GSRC>
__device__ __forceinline__ void dwt_level(const float* __restrict__ src,
                                          float* __restrict__ dst,
                                          int dband, float* __restrict__ red) {
    Acc aD = {0.f, 0.f, 0.f, 0.f, 0.f};
    Acc aA = {0.f, 0.f, 0.f, 0.f, 0.f};
    const int t = (int)threadIdx.x;
    constexpr int SN = o - S * (NT - 1);          // 19 / 13 / 10 / 6

    if (t < NT - 1) {
        constexpr int NF = S / 2 + 3;             // f4 loads (window 2S+12 floats)
        float v[4 * NF];
        const int w = 2 * S * t - 8;              // f4-aligned window start
        if (t == 0) {                             // left fold: load shifted, mirror
            #pragma unroll
            for (int q = 0; q < NF - 2; ++q) {
                float4 f;
                if constexpr (GSRC) f = *reinterpret_cast<const float4*>(src + 4 * q);
                else                f = lds_read4(src, q);
                v[8+4*q] = f.x; v[9+4*q] = f.y; v[10+4*q] = f.z; v[11+4*q] = f.w;
            }
            #pragma unroll
            for (int j = 0; j < 8; ++j) v[j] = v[15 - j];   // ext[-1-e] = s[e]
        } else {
            #pragma unroll
            for (int q = 0; q < NF; ++q) {
                float4 f;
                if constexpr (GSRC) f = *reinterpret_cast<const float4*>(src + w + 4 * q);
                else                f = lds_read4(src, (w >> 2) + q);
                v[4*q] = f.x; v[4*q+1] = f.y; v[4*q+2] = f.z; v[4*q+3] = f.w;
            }
        }
        span_core<S, true, LAST, true>(v, dst, S * t, aD, aA);
    } else if (t == NT - 1) {                     // tail: SN outputs, right fold
        constexpr int NFt = (2 * SN + 8 + 3) / 4;
        constexpr int p0 = S * (NT - 1);
        constexpr int w  = 2 * p0 - 8;
        constexpr int JM = L - w;                 // first mirrored v-index
        float v[4 * NFt];
        #pragma unroll
        for (int q = 0; q < NFt; ++q) {
            if (!GSRC || (w + 4 * q + 4 <= L)) {  // clamp global OOB (folds fill)
                float4 f;
                if constexpr (GSRC) f = *reinterpret_cast<const float4*>(src + w + 4 * q);
                else                f = lds_read4(src, (w >> 2) + q);
                v[4*q] = f.x; v[4*q+1] = f.y; v[4*q+2] = f.z; v[4*q+3] = f.w;
            }
        }
        #pragma unroll
        for (int j = JM; j < 4 * NFt; ++j)        // ext[L+e] = s[L-1-e]
            v[j] = v[2 * JM - 1 - j];
        span_core<SN, false, LAST, false>(v, dst, p0, aD, aA);
    }

    band_reduce(aD, dband, red);
    if constexpr (LAST) band_reduce(aA, 0, red);
}

__global__ void __launch_bounds__(BLK, 6)
wavelet_feat_kernel(const float* __restrict__ x, float* __restrict__ out) {
    // f4 counts padded so SWZ stays in-bounds (and tail over-reads are safe):
    // A: ceil(8195/4)=2049 -> 2056 f4; B: 1026 -> 1032 f4.  ~50.2KB total.
    __shared__ float4 A4[2056];
    __shared__ float4 B4[1032];
    __shared__ float red[5 * NW * 5];             // [band][wave][stat]
    float* A = reinterpret_cast<float*>(A4);
    float* B = reinterpret_cast<float*>(B4);

    const float* src0 = x + (size_t)blockIdx.x * T0;
    float* outp = out + (size_t)blockIdx.x * 30;

    // band index: 0=cA4 1=cD4 2=cD3 3=cD2 4=cD1
    dwt_level<16, 512, 16384, 8195, false, true >(src0, A, 4, red);  // L1: x->A
    __syncthreads();
    dwt_level< 8, 512,  8195, 4101, false, false>(A,    B, 3, red);  // L2: A->B
    __syncthreads();
    dwt_level< 4, 512,  4101, 2054, false, false>(B,    A, 2, red);  // L3: B->A
    __syncthreads();
    dwt_level< 4, 257,  2054, 1030, true,  false>(A, nullptr, 1, red); // L4 stats
    __syncthreads();                               // red[] complete

    if (threadIdx.x < 5) {
        const int band = (int)threadIdx.x;
        float a = 0.f, s = 0.f, q = 0.f, m = 0.f, z = 0.f;
        #pragma unroll
        for (int w = 0; w < NW; ++w) {
            const float* r = red + (band * NW + w) * 5;
            a += r[0]; s += r[1]; q += r[2]; m = fmaxf(m, r[3]); z += r[4];
        }
        const int o = (band <= 1) ? 1030 : (band == 2 ? 2054 : (band == 3 ? 4101 : 8195));
        const float inv  = 1.0f / (float)o;
        const float mean = s * inv;
        const float var  = q * inv - mean * mean;
        float* op = outp + band * 6;
        op[0] = a * inv;                  // mean_abs
        op[1] = sqrtf(fmaxf(var, 0.f));   // std (population)
        op[2] = sqrtf(q * inv);           // rms
        op[3] = m;                        // max_abs
        op[4] = q;                        // energy
        op[5] = z * inv;                  // zero-crossing rate
    }
}

extern "C" void kernel_launch(void* const* d_in, const int* in_sizes, int n_in,
                              void* d_out, int out_size, void* d_ws, size_t ws_size,
                              hipStream_t stream) {
    const float* x = (const float*)d_in[0];
    float* out = (float*)d_out;
    const int nsig = in_sizes[0] / T0;   // 64*64 = 4096
    hipLaunchKernelGGL(wavelet_feat_kernel, dim3(nsig), dim3(BLK), 0, stream, x, out);
}